// Round 3
// baseline (125.511 us; speedup 1.0000x reference)
//
#include <hip/hip_runtime.h>

// Problem constants (match reference)
#define DEPTH    257     // 256 train ids + OOV bucket
#define OUT_DIM  64
#define OOV_B    256
#define LUT_SIZE 512
#define TAB_ROWS 257     // bucket-space table rows
#define BLOCK    1024
#define GRID     512     // 2 blocks/CU (67.8 KB LDS each) -> 32 waves/CU

typedef float f32x4 __attribute__((ext_vector_type(4)));

// Single fused kernel:
//  stage:  sLut[513]  = lut (row 512 = OOV catch-all)      (2,052 B)
//          sTab[257][64] = W.T (bucket-major, contiguous)  (65,792 B)
//  loop:   id -> sLut -> sTab row quad -> nontemporal dwordx4 store.
// Two LDS hops (~120 cy each, batched x4 independent) replace any global
// gather; output stream is pure coalesced 16 B/lane stores.
__global__ __launch_bounds__(BLOCK, 8) void onehot_gather_kernel(
        const float* __restrict__ raw_ids,
        const float* __restrict__ W,
        const int* __restrict__ lut,
        f32x4* __restrict__ out4,
        int total_quads) {
    __shared__ float sTab[TAB_ROWS * OUT_DIM];   // 65,792 B
    __shared__ int   sLut[LUT_SIZE + 1];         // 2,052 B

    // Stage lut (+OOV sentinel at index 512 so min() handles all ids).
    for (int k = threadIdx.x; k <= LUT_SIZE; k += BLOCK)
        sLut[k] = (k < LUT_SIZE) ? lut[k] : OOV_B;
    // Stage W transposed: sTab[b*64+o] = W[o*257+b]. Strided global reads
    // (W is 65 KB, L2/LLC-resident chip-wide); contiguous LDS writes.
    for (int idx = threadIdx.x; idx < TAB_ROWS * OUT_DIM; idx += BLOCK) {
        int b = idx >> 6;          // bucket (0..256)
        int o = idx & 63;          // output dim
        sTab[idx] = W[o * DEPTH + b];
    }
    __syncthreads();

    const f32x4* sTab4 = (const f32x4*)sTab;
    const int stride = GRID * BLOCK;             // 524,288 quads = 8 MB/step
    int j = blockIdx.x * BLOCK + threadIdx.x;
    const int q = j & 15;                        // fixed per thread (stride%16==0)

    // x4 unrolled: 4 independent id loads -> 4 lut reads -> 4 table reads
    // -> 4 nt stores. 64 steps/thread total, 16 unrolled iterations.
    for (; j + 3 * stride < total_quads; j += 4 * stride) {
        int j0 = j, j1 = j + stride, j2 = j + 2 * stride, j3 = j + 3 * stride;
        float f0 = raw_ids[j0 >> 4];
        float f1 = raw_ids[j1 >> 4];
        float f2 = raw_ids[j2 >> 4];
        float f3 = raw_ids[j3 >> 4];
        unsigned i0 = min((unsigned)__float2int_rn(f0), (unsigned)LUT_SIZE);
        unsigned i1 = min((unsigned)__float2int_rn(f1), (unsigned)LUT_SIZE);
        unsigned i2 = min((unsigned)__float2int_rn(f2), (unsigned)LUT_SIZE);
        unsigned i3 = min((unsigned)__float2int_rn(f3), (unsigned)LUT_SIZE);
        int b0 = sLut[i0];
        int b1 = sLut[i1];
        int b2 = sLut[i2];
        int b3 = sLut[i3];
        f32x4 v0 = sTab4[b0 * 16 + q];
        f32x4 v1 = sTab4[b1 * 16 + q];
        f32x4 v2 = sTab4[b2 * 16 + q];
        f32x4 v3 = sTab4[b3 * 16 + q];
        __builtin_nontemporal_store(v0, &out4[j0]);
        __builtin_nontemporal_store(v1, &out4[j1]);
        __builtin_nontemporal_store(v2, &out4[j2]);
        __builtin_nontemporal_store(v3, &out4[j3]);
    }
    for (; j < total_quads; j += stride) {
        int id = __float2int_rn(raw_ids[j >> 4]);
        unsigned idx = min((unsigned)id, (unsigned)LUT_SIZE);
        int b = sLut[idx];
        __builtin_nontemporal_store(sTab4[b * 16 + (j & 15)], &out4[j]);
    }
}

extern "C" void kernel_launch(void* const* d_in, const int* in_sizes, int n_in,
                              void* d_out, int out_size, void* d_ws,
                              size_t ws_size, hipStream_t stream) {
    const float* raw_ids = (const float*)d_in[0];   // [N] f32 (integral values)
    const float* W       = (const float*)d_in[1];   // [64][257] f32
    const int*   lut     = (const int*)d_in[2];     // [512] i32
    float*       out     = (float*)d_out;           // [N][64] f32
    (void)d_ws; (void)ws_size;

    const int n = in_sizes[0];                      // 2,097,152
    const int total_quads = n * (OUT_DIM / 4);      // 33,554,432

    onehot_gather_kernel<<<GRID, BLOCK, 0, stream>>>(
        raw_ids, W, lut, (f32x4*)out, total_quads);
}

// Round 4
// 119.127 us; speedup vs baseline: 1.0536x; 1.0536x over previous
//
#include <hip/hip_runtime.h>

// Problem constants (match reference)
#define DEPTH    257     // 256 train ids + OOV
#define OUT_DIM  64
#define OOV_B    256
#define LUT_SIZE 512
#define FT_ROWS  513     // rows 0..511 = lut-mapped ids, row 512 = OOV catch-all
#define FT_QUADS (FT_ROWS * (OUT_DIM / 4))   // 8208 float4 = 131,328 B
#define BLOCK    1024
#define GRID     256     // 1 block/CU (131 KB LDS), 16 waves/CU (enough: fills hit 6.6TB/s @10% occ)

typedef float f32x4 __attribute__((ext_vector_type(4)));

// Prologue: fused table FT[id][o] = W[o][bucket(id)] for every possible raw
// id in [0,512], row 512 = OOV. One LDS hop in the hot loop.
__global__ void build_FT_kernel(const float* __restrict__ W,
                                const int* __restrict__ lut,
                                float* __restrict__ FT) {
    int idx = blockIdx.x * blockDim.x + threadIdx.x;
    if (idx >= FT_ROWS * OUT_DIM) return;
    int r = idx >> 6;                       // raw id (table row)
    int o = idx & 63;                       // output dim
    int bucket = (r < LUT_SIZE) ? lut[r] : OOV_B;
    FT[idx] = W[o * DEPTH + bucket];
}

// Main: FT staged in LDS (131 KB). Software-pipelined: next body's id loads
// are issued BEFORE the current body's stores, so the vmcnt wait for the
// loads never has to drain older stores (vmcnt is one in-order FIFO).
// Regular (cached) stores: ack at L2 acceptance, not HBM completion.
__global__ __launch_bounds__(BLOCK) void gather_lds_kernel(
        const float* __restrict__ raw_ids,
        const f32x4* __restrict__ FT4,
        f32x4* __restrict__ out4,
        int total_quads) {
    __shared__ f32x4 sFT[FT_QUADS];        // 131,328 B LDS
    for (int k = threadIdx.x; k < FT_QUADS; k += BLOCK) sFT[k] = FT4[k];
    __syncthreads();

    const int stride = GRID * BLOCK;       // 262,144 quads = 4 MB/step
    int j = blockIdx.x * BLOCK + threadIdx.x;
    const int q = j & 15;                  // fixed per thread (stride % 16 == 0)

    if (j + 3 * stride < total_quads) {
        // Pipeline prologue: preload body 0's ids.
        float f0 = raw_ids[j >> 4];
        float f1 = raw_ids[(j + stride) >> 4];
        float f2 = raw_ids[(j + 2 * stride) >> 4];
        float f3 = raw_ids[(j + 3 * stride) >> 4];

        int jc = j;
        // Steady state: resolve current body from regs, prefetch next body's
        // ids (loads issued before stores), then store current body.
        for (; jc + 7 * stride < total_quads; jc += 4 * stride) {
            int jn = jc + 4 * stride;
            unsigned u0 = min((unsigned)__float2int_rn(f0), (unsigned)LUT_SIZE);
            unsigned u1 = min((unsigned)__float2int_rn(f1), (unsigned)LUT_SIZE);
            unsigned u2 = min((unsigned)__float2int_rn(f2), (unsigned)LUT_SIZE);
            unsigned u3 = min((unsigned)__float2int_rn(f3), (unsigned)LUT_SIZE);
            f32x4 v0 = sFT[u0 * 16 + q];
            f32x4 v1 = sFT[u1 * 16 + q];
            f32x4 v2 = sFT[u2 * 16 + q];
            f32x4 v3 = sFT[u3 * 16 + q];
            // prefetch next body (global loads BEFORE this body's stores)
            f0 = raw_ids[jn >> 4];
            f1 = raw_ids[(jn + stride) >> 4];
            f2 = raw_ids[(jn + 2 * stride) >> 4];
            f3 = raw_ids[(jn + 3 * stride) >> 4];
            out4[jc]              = v0;
            out4[jc + stride]     = v1;
            out4[jc + 2 * stride] = v2;
            out4[jc + 3 * stride] = v3;
        }
        // Pipeline epilogue: last full body (already loaded).
        {
            unsigned u0 = min((unsigned)__float2int_rn(f0), (unsigned)LUT_SIZE);
            unsigned u1 = min((unsigned)__float2int_rn(f1), (unsigned)LUT_SIZE);
            unsigned u2 = min((unsigned)__float2int_rn(f2), (unsigned)LUT_SIZE);
            unsigned u3 = min((unsigned)__float2int_rn(f3), (unsigned)LUT_SIZE);
            out4[jc]              = sFT[u0 * 16 + q];
            out4[jc + stride]     = sFT[u1 * 16 + q];
            out4[jc + 2 * stride] = sFT[u2 * 16 + q];
            out4[jc + 3 * stride] = sFT[u3 * 16 + q];
            jc += 4 * stride;
        }
        j = jc;
    }
    // Generic tail (empty for N = 2M, but keeps the kernel shape-correct).
    for (; j < total_quads; j += stride) {
        int id = __float2int_rn(raw_ids[j >> 4]);
        unsigned idx = min((unsigned)id, (unsigned)LUT_SIZE);
        out4[j] = sFT[idx * 16 + (j & 15)];
    }
}

// Fallback if ws is too small for FT: direct strided gather from W.
__global__ void gather_rows_direct_kernel(const float* __restrict__ raw_ids,
                                          const float* __restrict__ W,
                                          const int* __restrict__ lut,
                                          float4* __restrict__ out4,
                                          int total_quads) {
    int stride = gridDim.x * blockDim.x;
    for (int j = blockIdx.x * blockDim.x + threadIdx.x; j < total_quads;
         j += stride) {
        int row = j >> 4;
        int q   = j & 15;
        int id  = __float2int_rn(raw_ids[row]);
        int bucket = ((unsigned)id < LUT_SIZE) ? lut[id] : OOV_B;
        float4 v;
        v.x = W[(4 * q + 0) * DEPTH + bucket];
        v.y = W[(4 * q + 1) * DEPTH + bucket];
        v.z = W[(4 * q + 2) * DEPTH + bucket];
        v.w = W[(4 * q + 3) * DEPTH + bucket];
        out4[j] = v;
    }
}

extern "C" void kernel_launch(void* const* d_in, const int* in_sizes, int n_in,
                              void* d_out, int out_size, void* d_ws,
                              size_t ws_size, hipStream_t stream) {
    const float* raw_ids = (const float*)d_in[0];   // [N] f32 (integral values)
    const float* W       = (const float*)d_in[1];   // [64][257] f32
    const int*   lut     = (const int*)d_in[2];     // [512] i32
    float*       out     = (float*)d_out;           // [N][64] f32

    const int n = in_sizes[0];                      // 2,097,152
    const int total_quads = n * (OUT_DIM / 4);      // 33,554,432

    const size_t ft_bytes = (size_t)FT_ROWS * OUT_DIM * sizeof(float);
    if (ws_size >= ft_bytes) {
        float* FT = (float*)d_ws;
        const int ttotal = FT_ROWS * OUT_DIM;       // 32,832
        build_FT_kernel<<<(ttotal + 255) / 256, 256, 0, stream>>>(W, lut, FT);
        gather_lds_kernel<<<GRID, BLOCK, 0, stream>>>(
            raw_ids, (const f32x4*)FT, (f32x4*)out, total_quads);
    } else {
        gather_rows_direct_kernel<<<2048, 256, 0, stream>>>(
            raw_ids, W, lut, (float4*)out, total_quads);
    }
}

// Round 5
// 114.180 us; speedup vs baseline: 1.0992x; 1.0433x over previous
//
#include <hip/hip_runtime.h>

// Problem constants (match reference)
#define DEPTH    257     // 256 train ids + OOV
#define OUT_DIM  64
#define OOV_B    256
#define LUT_SIZE 512
#define FT_ROWS  513     // rows 0..511 = lut-mapped ids, row 512 = OOV catch-all
#define FT_QUADS (FT_ROWS * (OUT_DIM / 4))   // 8208 float4 = 131,328 B
#define BLOCK    1024
#define GRID     256     // 1 block/CU (131 KB LDS)
#define G_STEP   ((GRID * BLOCK) / 16)       // 16384 row-groups (of 4 rows) per grid step

typedef float f32x4 __attribute__((ext_vector_type(4)));

// Prologue: fused table FT[id][o] = W[o][bucket(id)] for every raw id in
// [0,512], row 512 = OOV catch-all. One LDS hop in the hot loop.
__global__ void build_FT_kernel(const float* __restrict__ W,
                                const int* __restrict__ lut,
                                float* __restrict__ FT) {
    int idx = blockIdx.x * blockDim.x + threadIdx.x;
    if (idx >= FT_ROWS * OUT_DIM) return;
    int r = idx >> 6;                       // raw id (table row)
    int o = idx & 63;                       // output dim
    int bucket = (r < LUT_SIZE) ? lut[r] : OOV_B;
    FT[idx] = W[o * DEPTH + bucket];
}

// Main (R2 structure, reduced per-body overhead):
//  - thread t owns quad q = t&15 of 4 CONSECUTIVE rows per body
//    -> ids arrive as ONE float4 load (uniform per 16-lane group, 64B/wave)
//    -> 4 NT stores share one base address + 256B immediate offsets
//    -> wave store = 4 x 256B contiguous chunks (full-line writes)
//  - x2 unrolled: both id float4 loads issued before either body's work.
__global__ __launch_bounds__(BLOCK) void gather_lds_kernel(
        const float4* __restrict__ raw4,     // raw_ids viewed as [N/4] float4
        const f32x4* __restrict__ FT4,
        f32x4* __restrict__ out4,
        int n_rows) {
    __shared__ f32x4 sFT[FT_QUADS];          // 131,328 B LDS
    for (int k = threadIdx.x; k < FT_QUADS; k += BLOCK) sFT[k] = FT4[k];
    __syncthreads();

    const int t = blockIdx.x * BLOCK + threadIdx.x;
    const int q = t & 15;                    // quad within row (fixed per thread)
    int g = t >> 4;                          // row-group (4 rows) index
    const int ngroups = n_rows >> 2;         // 524,288

    // Steady state: 32 steps for N=2M -> 16 x2-unrolled iterations.
    for (; g + G_STEP < ngroups; g += 2 * G_STEP) {
        float4 fa = raw4[g];                 // ids for rows 4g..4g+3
        float4 fb = raw4[g + G_STEP];        // next body's ids (issued early)

        unsigned a0 = min((unsigned)__float2int_rn(fa.x), (unsigned)LUT_SIZE);
        unsigned a1 = min((unsigned)__float2int_rn(fa.y), (unsigned)LUT_SIZE);
        unsigned a2 = min((unsigned)__float2int_rn(fa.z), (unsigned)LUT_SIZE);
        unsigned a3 = min((unsigned)__float2int_rn(fa.w), (unsigned)LUT_SIZE);
        f32x4 va0 = sFT[a0 * 16 + q];
        f32x4 va1 = sFT[a1 * 16 + q];
        f32x4 va2 = sFT[a2 * 16 + q];
        f32x4 va3 = sFT[a3 * 16 + q];
        int base_a = g * 64 + q;             // out4 index of (row 4g, quad q)
        __builtin_nontemporal_store(va0, &out4[base_a]);
        __builtin_nontemporal_store(va1, &out4[base_a + 16]);
        __builtin_nontemporal_store(va2, &out4[base_a + 32]);
        __builtin_nontemporal_store(va3, &out4[base_a + 48]);

        unsigned b0 = min((unsigned)__float2int_rn(fb.x), (unsigned)LUT_SIZE);
        unsigned b1 = min((unsigned)__float2int_rn(fb.y), (unsigned)LUT_SIZE);
        unsigned b2 = min((unsigned)__float2int_rn(fb.z), (unsigned)LUT_SIZE);
        unsigned b3 = min((unsigned)__float2int_rn(fb.w), (unsigned)LUT_SIZE);
        f32x4 vb0 = sFT[b0 * 16 + q];
        f32x4 vb1 = sFT[b1 * 16 + q];
        f32x4 vb2 = sFT[b2 * 16 + q];
        f32x4 vb3 = sFT[b3 * 16 + q];
        int base_b = (g + G_STEP) * 64 + q;
        __builtin_nontemporal_store(vb0, &out4[base_b]);
        __builtin_nontemporal_store(vb1, &out4[base_b + 16]);
        __builtin_nontemporal_store(vb2, &out4[base_b + 32]);
        __builtin_nontemporal_store(vb3, &out4[base_b + 48]);
    }
    // Tail (empty for N = 2M, kept for shape-correctness).
    for (; g < ngroups; g += G_STEP) {
        float4 f = raw4[g];
        unsigned c0 = min((unsigned)__float2int_rn(f.x), (unsigned)LUT_SIZE);
        unsigned c1 = min((unsigned)__float2int_rn(f.y), (unsigned)LUT_SIZE);
        unsigned c2 = min((unsigned)__float2int_rn(f.z), (unsigned)LUT_SIZE);
        unsigned c3 = min((unsigned)__float2int_rn(f.w), (unsigned)LUT_SIZE);
        int base = g * 64 + q;
        __builtin_nontemporal_store(sFT[c0 * 16 + q], &out4[base]);
        __builtin_nontemporal_store(sFT[c1 * 16 + q], &out4[base + 16]);
        __builtin_nontemporal_store(sFT[c2 * 16 + q], &out4[base + 32]);
        __builtin_nontemporal_store(sFT[c3 * 16 + q], &out4[base + 48]);
    }
}

// Fallback if ws is too small for FT: direct strided gather from W.
__global__ void gather_rows_direct_kernel(const float* __restrict__ raw_ids,
                                          const float* __restrict__ W,
                                          const int* __restrict__ lut,
                                          float4* __restrict__ out4,
                                          int total_quads) {
    int stride = gridDim.x * blockDim.x;
    for (int j = blockIdx.x * blockDim.x + threadIdx.x; j < total_quads;
         j += stride) {
        int row = j >> 4;
        int qq  = j & 15;
        int id  = __float2int_rn(raw_ids[row]);
        int bucket = ((unsigned)id < LUT_SIZE) ? lut[id] : OOV_B;
        float4 v;
        v.x = W[(4 * qq + 0) * DEPTH + bucket];
        v.y = W[(4 * qq + 1) * DEPTH + bucket];
        v.z = W[(4 * qq + 2) * DEPTH + bucket];
        v.w = W[(4 * qq + 3) * DEPTH + bucket];
        out4[j] = v;
    }
}

extern "C" void kernel_launch(void* const* d_in, const int* in_sizes, int n_in,
                              void* d_out, int out_size, void* d_ws,
                              size_t ws_size, hipStream_t stream) {
    const float* raw_ids = (const float*)d_in[0];   // [N] f32 (integral values)
    const float* W       = (const float*)d_in[1];   // [64][257] f32
    const int*   lut     = (const int*)d_in[2];     // [512] i32
    float*       out     = (float*)d_out;           // [N][64] f32

    const int n = in_sizes[0];                      // 2,097,152 (divisible by 4)

    const size_t ft_bytes = (size_t)FT_ROWS * OUT_DIM * sizeof(float);
    if (ws_size >= ft_bytes && (n & 3) == 0) {
        float* FT = (float*)d_ws;
        const int ttotal = FT_ROWS * OUT_DIM;       // 32,832
        build_FT_kernel<<<(ttotal + 255) / 256, 256, 0, stream>>>(W, lut, FT);
        gather_lds_kernel<<<GRID, BLOCK, 0, stream>>>(
            (const float4*)raw_ids, (const f32x4*)FT, (f32x4*)out, n);
    } else {
        gather_rows_direct_kernel<<<2048, 256, 0, stream>>>(
            raw_ids, W, lut, (float4*)out, n * (OUT_DIM / 4));
    }
}

// Round 6
// 111.466 us; speedup vs baseline: 1.1260x; 1.0243x over previous
//
#include <hip/hip_runtime.h>

// Problem constants (match reference)
#define DEPTH    257     // 256 train ids + OOV
#define OUT_DIM  64
#define OOV_B    256
#define LUT_SIZE 512
#define FT_ROWS  513     // rows 0..511 = lut-mapped raw ids, row 512 = OOV catch-all
#define FT_QUADS (FT_ROWS * 16)              // 8208 float4 = 131,328 B
#define BLOCK    1024
#define GRID     256                         // 1 block/CU (131 KB LDS)

typedef float f32x4 __attribute__((ext_vector_type(4)));

// Single fused kernel.
//  Staging (in-block, no prologue kernel): sFT[r*16+qq] = W.T row for
//  bucket(lut[r]) — 4 strided W reads (L2-resident 65KB) + 1 ds_write_b128,
//  conflict-free (consecutive threads -> consecutive LDS quads).
//  Hot loop: EXACT R2 body (x4 strided unroll, scalar id loads, one LDS hop,
//  NT stores = 1KB contiguous per wave-store), plus a depth-2 register
//  pipeline on the id loads: body k+2's ids are issued BEFORE body k's
//  stores, so the vmcnt wait for ids never drains young stores and each id
//  load has ~2 body-times to complete.
__global__ __launch_bounds__(BLOCK) void onehot_fused_kernel(
        const float* __restrict__ raw_ids,
        const float* __restrict__ W,
        const int* __restrict__ lut,
        f32x4* __restrict__ out4,
        int total_quads) {
    __shared__ f32x4 sFT[FT_QUADS];          // 131,328 B LDS

    // ---- fused staging ----
    for (int k = threadIdx.x; k < FT_QUADS; k += BLOCK) {
        int r  = k >> 4;                     // raw id (table row)
        int qq = k & 15;                     // quad within row
        int bucket = (r < LUT_SIZE) ? lut[r] : OOV_B;
        f32x4 v;
        v.x = W[(4 * qq + 0) * DEPTH + bucket];
        v.y = W[(4 * qq + 1) * DEPTH + bucket];
        v.z = W[(4 * qq + 2) * DEPTH + bucket];
        v.w = W[(4 * qq + 3) * DEPTH + bucket];
        sFT[k] = v;
    }
    __syncthreads();

    // ---- hot loop ----
    const int stride = GRID * BLOCK;         // 262,144 quads = 4 MB/step
    const int j0 = blockIdx.x * BLOCK + threadIdx.x;
    const int q  = j0 & 15;                  // invariant (stride % 16 == 0)

    // Number of FULL x4 bodies for this thread (32 for N = 2M, uniform).
    int full = 0;
    if (total_quads > j0 + 3 * stride)
        full = (total_quads - 1 - j0 - 3 * stride) / (4 * stride) + 1;

    int jj = j0;
    // Pipeline prologue: preload ids for bodies 0 and 1.
    float a0 = 0.f, a1 = 0.f, a2 = 0.f, a3 = 0.f;   // body k   ids
    float b0 = 0.f, b1 = 0.f, b2 = 0.f, b3 = 0.f;   // body k+1 ids
    if (full > 0) {
        a0 = raw_ids[jj >> 4];
        a1 = raw_ids[(jj + stride) >> 4];
        a2 = raw_ids[(jj + 2 * stride) >> 4];
        a3 = raw_ids[(jj + 3 * stride) >> 4];
    }
    if (full > 1) {
        int jn = jj + 4 * stride;
        b0 = raw_ids[jn >> 4];
        b1 = raw_ids[(jn + stride) >> 4];
        b2 = raw_ids[(jn + 2 * stride) >> 4];
        b3 = raw_ids[(jn + 3 * stride) >> 4];
    }

    for (int k = 0; k < full; ++k) {
        // resolve current body from registers
        unsigned u0 = min((unsigned)__float2int_rn(a0), (unsigned)LUT_SIZE);
        unsigned u1 = min((unsigned)__float2int_rn(a1), (unsigned)LUT_SIZE);
        unsigned u2 = min((unsigned)__float2int_rn(a2), (unsigned)LUT_SIZE);
        unsigned u3 = min((unsigned)__float2int_rn(a3), (unsigned)LUT_SIZE);
        f32x4 v0 = sFT[u0 * 16 + q];
        f32x4 v1 = sFT[u1 * 16 + q];
        f32x4 v2 = sFT[u2 * 16 + q];
        f32x4 v3 = sFT[u3 * 16 + q];

        // rotate pipeline and issue body k+2's id loads (BEFORE stores)
        a0 = b0; a1 = b1; a2 = b2; a3 = b3;
        if (k + 2 < full) {
            int jn = jj + 8 * stride;
            b0 = raw_ids[jn >> 4];
            b1 = raw_ids[(jn + stride) >> 4];
            b2 = raw_ids[(jn + 2 * stride) >> 4];
            b3 = raw_ids[(jn + 3 * stride) >> 4];
        }

        // store current body (wave store = 1 KB contiguous, nontemporal)
        __builtin_nontemporal_store(v0, &out4[jj]);
        __builtin_nontemporal_store(v1, &out4[jj + stride]);
        __builtin_nontemporal_store(v2, &out4[jj + 2 * stride]);
        __builtin_nontemporal_store(v3, &out4[jj + 3 * stride]);
        jj += 4 * stride;
    }

    // Generic tail (empty for N = 2M).
    for (int j = jj; j < total_quads; j += stride) {
        int id = __float2int_rn(raw_ids[j >> 4]);
        unsigned idx = min((unsigned)id, (unsigned)LUT_SIZE);
        __builtin_nontemporal_store(sFT[idx * 16 + q], &out4[j]);
    }
}

extern "C" void kernel_launch(void* const* d_in, const int* in_sizes, int n_in,
                              void* d_out, int out_size, void* d_ws,
                              size_t ws_size, hipStream_t stream) {
    const float* raw_ids = (const float*)d_in[0];   // [N] f32 (integral values)
    const float* W       = (const float*)d_in[1];   // [64][257] f32
    const int*   lut     = (const int*)d_in[2];     // [512] i32
    float*       out     = (float*)d_out;           // [N][64] f32
    (void)d_ws; (void)ws_size;

    const int n = in_sizes[0];                      // 2,097,152
    const int total_quads = n * (OUT_DIM / 4);      // 33,554,432

    onehot_fused_kernel<<<GRID, BLOCK, 0, stream>>>(
        raw_ids, W, lut, (f32x4*)out, total_quads);
}